// Round 1
// baseline (1266.725 us; speedup 1.0000x reference)
//
#include <hip/hip_runtime.h>

#define W 512
#define NPX (512*512)
#define NCH 48
#define NBATCH 16

// reflect-101 index mapping into [0,511]; valid for i in [-511, 1022]
__device__ __forceinline__ int refl(int i) {
    int a = i < 0 ? -i : i;
    int b = 1022 - a;
    return a < b ? a : b;
}
__device__ __forceinline__ unsigned encf(float f) {
    unsigned u = __float_as_uint(f);
    return (u & 0x80000000u) ? ~u : (u | 0x80000000u);
}
__device__ __forceinline__ float decf(unsigned e) {
    unsigned u = (e & 0x80000000u) ? (e & 0x7FFFFFFFu) : ~e;
    return __uint_as_float(u);
}
__device__ __forceinline__ unsigned long long enc64(double d) {
    unsigned long long u = (unsigned long long)__double_as_longlong(d);
    return (u & 0x8000000000000000ULL) ? ~u : (u | 0x8000000000000000ULL);
}
__device__ __forceinline__ double dec64(unsigned long long e) {
    unsigned long long u = (e & 0x8000000000000000ULL) ? (e & 0x7FFFFFFFFFFFFFFFULL) : ~e;
    return __longlong_as_double((long long)u);
}

__global__ void initK(unsigned* minenc, unsigned* maxenc, unsigned long long* rmaxenc) {
    int t = threadIdx.x;
    if (t < NCH) { minenc[t] = 0xFFFFFFFFu; maxenc[t] = 0u; rmaxenc[t] = 0ULL; }
}

// weights, zero-padded with 3 zeros on each side: gw[o*280 + 3 + k] = g[k], k in [0,2r]
__global__ void gaussK(float* gw) {
    int o = blockIdx.x;
    const int rr[6] = {4, 8, 17, 34, 67, 134};
    int r = rr[o];
    float sigma = 1.4f * (float)(1 << o);
    int t = threadIdx.x;   // 512
    int n = 2*r + 1;
    float wv = 0.f;
    if (t < n) { float ft = (float)(t - r) / sigma; wv = expf(-0.5f * ft * ft); }
    __shared__ float red[512];
    red[t] = wv; __syncthreads();
    for (int s = 256; s > 0; s >>= 1) { if (t < s) red[t] += red[t + s]; __syncthreads(); }
    float sum = red[0];
    float* g = gw + o*280;
    for (int i = t; i < 280; i += 512) g[i] = 0.f;
    __syncthreads();
    if (t < n) g[3 + t] = wv / sum;
}

__global__ void minmaxK(const float4* __restrict__ x4, unsigned* minenc, unsigned* maxenc) {
    int ch = blockIdx.y, chunk = blockIdx.x, t = threadIdx.x;
    size_t base = (size_t)ch*(NPX/4) + (size_t)chunk*8192;
    float mn = 3.4e38f, mx = -3.4e38f;
    for (int i = t; i < 8192; i += 256) {
        float4 v = x4[base + i];
        mn = fminf(mn, fminf(fminf(v.x, v.y), fminf(v.z, v.w)));
        mx = fmaxf(mx, fmaxf(fmaxf(v.x, v.y), fmaxf(v.z, v.w)));
    }
    for (int o = 32; o; o >>= 1) { mn = fminf(mn, __shfl_down(mn, o)); mx = fmaxf(mx, __shfl_down(mx, o)); }
    __shared__ float smn[4], smx[4];
    if ((t & 63) == 0) { smn[t >> 6] = mn; smx[t >> 6] = mx; }
    __syncthreads();
    if (t == 0) {
        for (int i = 1; i < 4; i++) { mn = fminf(mn, smn[i]); mx = fmaxf(mx, smx[i]); }
        atomicMin(&minenc[ch], encf(mn));
        atomicMax(&maxenc[ch], encf(mx));
    }
}

__global__ void scaleK(const unsigned* minenc, const unsigned* maxenc, double* gsd) {
    int t = threadIdx.x;
    if (t >= NCH) return;
    double mn = (double)decf(minenc[t]), mx = (double)decf(maxenc[t]);
    gsd[t] = 255.0 / (mx - mn + 1e-12);
}

// Harris R (fp64, box reflects ARRAY positions) + Laplacian base (fp32) + per-channel max R
__global__ void lapRK(const float* __restrict__ x, const double* __restrict__ gsd,
                      float* __restrict__ lap, double* __restrict__ Rb,
                      unsigned long long* __restrict__ rmaxenc) {
    int ch = blockIdx.y;
    int p = blockIdx.x*256 + threadIdx.x;
    int py = p >> 9, px = p & 511;
    const float* s = x + (size_t)ch*NPX;
    double sd = gsd[ch];
    auto rd = [&](int yy, int xx) -> double { return (double)s[refl(yy)*W + refl(xx)]; };
    // box-2x2 source positions: {reflect-of-array(py-1), py} x {reflect(px-1), px}
    int ylist[2] = { py ? py-1 : 1, py };
    int xlist[2] = { px ? px-1 : 1, px };
    double Sxx = 0, Syy = 0, Sxy = 0;
    #pragma unroll
    for (int a = 0; a < 2; a++) {
        #pragma unroll
        for (int bb = 0; bb < 2; bb++) {
            int yy = ylist[a], xx = xlist[bb];
            double v00 = rd(yy-1, xx-1), v01 = rd(yy-1, xx), v02 = rd(yy-1, xx+1);
            double v10 = rd(yy,   xx-1),                     v12 = rd(yy,   xx+1);
            double v20 = rd(yy+1, xx-1), v21 = rd(yy+1, xx), v22 = rd(yy+1, xx+1);
            double ix = (v02 + 2.0*v12 + v22) - (v00 + 2.0*v10 + v20);
            double iy = (v20 + 2.0*v21 + v22) - (v00 + 2.0*v01 + v02);
            Sxx += ix*ix; Syy += iy*iy; Sxy += ix*iy;
        }
    }
    double s2 = sd * sd;
    Sxx *= s2; Syy *= s2; Sxy *= s2;
    double tr = Sxx + Syy;
    double R = Sxx*Syy - Sxy*Sxy - 0.04*tr*tr;
    Rb[(size_t)ch*NPX + p] = R;
    double l = 2.0*(rd(py-1,px-1) + rd(py-1,px+1) + rd(py+1,px-1) + rd(py+1,px+1)) - 8.0*rd(py,px);
    lap[(size_t)ch*NPX + p] = (float)(sd * l);
    double m = R;
    for (int o = 32; o; o >>= 1) m = fmax(m, __shfl_down(m, o));
    __shared__ double sred[4];
    if ((threadIdx.x & 63) == 0) sred[threadIdx.x >> 6] = m;
    __syncthreads();
    if (threadIdx.x == 0) {
        for (int i = 1; i < 4; i++) m = fmax(m, sred[i]);
        atomicMax(&rmaxenc[ch], enc64(m));
    }
}

// dilate 3x3 (clamped window == -inf SAME pad) + threshold -> byte mask
__global__ void maskK(const double* __restrict__ Rb, const unsigned long long* __restrict__ rmaxenc,
                      unsigned char* __restrict__ maskb) {
    int ch = blockIdx.y;
    int p = blockIdx.x*256 + threadIdx.x;
    int py = p >> 9, px = p & 511;
    double thr = 0.01 * dec64(rmaxenc[ch]);
    const double* R = Rb + (size_t)ch*NPX;
    double mv = -1e308;
    #pragma unroll
    for (int dy = -1; dy <= 1; dy++) {
        int yy = py + dy;
        if ((unsigned)yy < 512u) {
            #pragma unroll
            for (int dx = -1; dx <= 1; dx++) {
                int xx = px + dx;
                if ((unsigned)xx < 512u) mv = fmax(mv, R[yy*W + xx]);
            }
        }
    }
    maskb[(size_t)ch*NPX + p] = (mv > thr) ? 1 : 0;
}

// horizontal blur: 4 rows/block, 4 px/thread sliding window, float4 LDS reads
__global__ __launch_bounds__(512) void rowblurK(const float* __restrict__ src, float* __restrict__ dst,
                                                const float* __restrict__ gw, int r) {
    int ch = blockIdx.y;
    int row0 = blockIdx.x * 4;
    int t = threadIdx.x;
    int lr = t >> 7, xi = t & 127;
    __shared__ float ext[4][788];
    const float* s = src + (size_t)ch*NPX + (size_t)(row0 + lr)*W;
    int n = W + 2*r;
    for (int i = xi; i < 788; i += 128) {
        float v = 0.f;
        if (i < n) v = s[refl(i - r)];
        ext[lr][i] = v;
    }
    __syncthreads();
    const float* E = ext[lr];
    const float4* E4 = (const float4*)E;
    float a0 = 0, a1 = 0, a2 = 0, a3 = 0;
    int nb = (2*r + 7) >> 2;
    for (int c2 = 0; c2 < nb; ++c2) {
        float4 f = E4[xi + c2];
        const float* g0 = gw + 4*c2;   // g0[3+u-m] pattern, weights pre-padded with zeros
        a0 = fmaf(g0[3], f.x, a0); a1 = fmaf(g0[2], f.x, a1); a2 = fmaf(g0[1], f.x, a2); a3 = fmaf(g0[0], f.x, a3);
        a0 = fmaf(g0[4], f.y, a0); a1 = fmaf(g0[3], f.y, a1); a2 = fmaf(g0[2], f.y, a2); a3 = fmaf(g0[1], f.y, a3);
        a0 = fmaf(g0[5], f.z, a0); a1 = fmaf(g0[4], f.z, a1); a2 = fmaf(g0[3], f.z, a2); a3 = fmaf(g0[2], f.z, a3);
        a0 = fmaf(g0[6], f.w, a0); a1 = fmaf(g0[5], f.w, a1); a2 = fmaf(g0[4], f.w, a2); a3 = fmaf(g0[3], f.w, a3);
    }
    *(float4*)&dst[(size_t)ch*NPX + (size_t)(row0 + lr)*W + xi*4] = make_float4(a0, a1, a2, a3);
}

// vertical blur + mask + sigma*|.| + channel-max + octave-max into out
__global__ __launch_bounds__(256) void colblurK(const float* __restrict__ T, const unsigned char* __restrict__ maskb,
                                                float* __restrict__ out, const float* __restrict__ gw,
                                                int r, float sigma, int write0) {
    extern __shared__ float tile[];   // [rowsA][32]
    int x0 = blockIdx.x * 32;
    int band0 = blockIdx.y * 128;
    int b = blockIdx.z;
    int t = threadIdx.x;
    int tx = t & 31, ys = t >> 5;
    int rowsData = 128 + 2*r;
    int rowsA = rowsData + 4;
    float vm[4][4];
    #pragma unroll
    for (int q = 0; q < 4; q++) { vm[q][0] = 0; vm[q][1] = 0; vm[q][2] = 0; vm[q][3] = 0; }
    for (int c = 0; c < 3; ++c) {
        int ch = b*3 + c;
        __syncthreads();
        const float* src = T + (size_t)ch*NPX;
        for (int i = t; i < rowsA*32; i += 256) {
            int ly = i >> 5, x = i & 31;
            float v = 0.f;
            if (ly < rowsData) v = src[(size_t)refl(band0 - r + ly)*W + x0 + x];
            tile[i] = v;
        }
        __syncthreads();
        const unsigned char* mrow = maskb + (size_t)ch*NPX;
        #pragma unroll
        for (int q = 0; q < 4; ++q) {
            int j0 = ys*16 + q*4;
            int gy0 = band0 + j0;
            unsigned m0 = mrow[(size_t)(gy0+0)*W + x0 + tx];
            unsigned m1 = mrow[(size_t)(gy0+1)*W + x0 + tx];
            unsigned m2 = mrow[(size_t)(gy0+2)*W + x0 + tx];
            unsigned m3 = mrow[(size_t)(gy0+3)*W + x0 + tx];
            if (__any((int)(m0 | m1 | m2 | m3))) {
                float a0 = 0, a1 = 0, a2 = 0, a3 = 0;
                int nu = 2*r + 4;
                #pragma unroll 4
                for (int u = 0; u < nu; ++u) {
                    float f = tile[(j0 + u)*32 + tx];
                    const float* g0 = gw + u;
                    a0 = fmaf(g0[3], f, a0);
                    a1 = fmaf(g0[2], f, a1);
                    a2 = fmaf(g0[1], f, a2);
                    a3 = fmaf(g0[0], f, a3);
                }
                if (m0) vm[q][0] = fmaxf(vm[q][0], sigma*fabsf(a0));
                if (m1) vm[q][1] = fmaxf(vm[q][1], sigma*fabsf(a1));
                if (m2) vm[q][2] = fmaxf(vm[q][2], sigma*fabsf(a2));
                if (m3) vm[q][3] = fmaxf(vm[q][3], sigma*fabsf(a3));
            }
        }
    }
    float* ob = out + (size_t)b*NPX;
    #pragma unroll
    for (int q = 0; q < 4; q++) {
        int j0 = ys*16 + q*4;
        #pragma unroll
        for (int m = 0; m < 4; m++) {
            size_t idx = (size_t)(band0 + j0 + m)*W + x0 + tx;
            float v = vm[q][m];
            if (!write0) v = fmaxf(v, ob[idx]);
            ob[idx] = v;
        }
    }
}

extern "C" void kernel_launch(void* const* d_in, const int* in_sizes, int n_in,
                              void* d_out, int out_size, void* d_ws, size_t ws_size,
                              hipStream_t stream) {
    const float* x = (const float*)d_in[0];
    float* out = (float*)d_out;
    char* w = (char*)d_ws;
    // ws layout (needs ~156 MiB):
    unsigned* minenc           = (unsigned*)(w + 1024);
    unsigned* maxenc           = (unsigned*)(w + 1280);
    unsigned long long* rmaxenc= (unsigned long long*)(w + 1536);
    double*  gsd               = (double*)(w + 256);
    float*   gw                = (float*)(w + 2048);                 // 6*280 floats
    float*   lap               = (float*)(w + 16384);                // 50331648 B
    double*  Rb                = (double*)(w + 16384 + 50331648);    // 100663296 B
    float*   T                 = (float*)Rb;                         // reused after maskK
    unsigned char* maskb       = (unsigned char*)(w + 16384 + 50331648 + 100663296); // 12582912 B

    initK<<<1, 64, 0, stream>>>(minenc, maxenc, rmaxenc);
    gaussK<<<6, 512, 0, stream>>>(gw);
    minmaxK<<<dim3(8, 48), 256, 0, stream>>>((const float4*)x, minenc, maxenc);
    scaleK<<<1, 64, 0, stream>>>(minenc, maxenc, gsd);
    lapRK<<<dim3(1024, 48), 256, 0, stream>>>(x, gsd, lap, Rb, rmaxenc);
    maskK<<<dim3(1024, 48), 256, 0, stream>>>(Rb, rmaxenc, maskb);

    const int rr[6] = {4, 8, 17, 34, 67, 134};
    for (int o = 0; o < 6; ++o) {
        int r = rr[o];
        float sigma = 1.4f * (float)(1 << o);
        rowblurK<<<dim3(128, 48), 512, 0, stream>>>(lap, T, gw + o*280, r);
        int rowsA = 128 + 2*r + 4;
        size_t lds = (size_t)rowsA * 32 * 4;
        colblurK<<<dim3(16, 4, 16), 256, lds, stream>>>(T, maskb, out, gw + o*280, r, sigma, o == 0 ? 1 : 0);
    }
}

// Round 2
// 993.200 us; speedup vs baseline: 1.2754x; 1.2754x over previous
//
#include <hip/hip_runtime.h>

#define W 512
#define NPX (512*512)
#define NCH 48
#define NBATCH 16

// reflect-101 index mapping into [0,511]; valid for i in [-511, 1022]
__device__ __forceinline__ int refl(int i) {
    int a = i < 0 ? -i : i;
    int b = 1022 - a;
    return a < b ? a : b;
}
__device__ __forceinline__ unsigned encf(float f) {
    unsigned u = __float_as_uint(f);
    return (u & 0x80000000u) ? ~u : (u | 0x80000000u);
}
__device__ __forceinline__ float decf(unsigned e) {
    unsigned u = (e & 0x80000000u) ? (e & 0x7FFFFFFFu) : ~e;
    return __uint_as_float(u);
}
__device__ __forceinline__ unsigned long long enc64(double d) {
    unsigned long long u = (unsigned long long)__double_as_longlong(d);
    return (u & 0x8000000000000000ULL) ? ~u : (u | 0x8000000000000000ULL);
}
__device__ __forceinline__ double dec64(unsigned long long e) {
    unsigned long long u = (e & 0x8000000000000000ULL) ? (e & 0x7FFFFFFFFFFFFFFFULL) : ~e;
    return __longlong_as_double((long long)u);
}

__global__ void initK(unsigned* minenc, unsigned* maxenc, unsigned long long* rmaxenc) {
    int t = threadIdx.x;
    if (t < NCH) { minenc[t] = 0xFFFFFFFFu; maxenc[t] = 0u; rmaxenc[t] = 0ULL; }
}

// weights, zero-padded with 3 zeros on each side: gw[o*280 + 3 + k] = g[k], k in [0,2r]
__global__ void gaussK(float* gw) {
    int o = blockIdx.x;
    const int rr[6] = {4, 8, 17, 34, 67, 134};
    int r = rr[o];
    float sigma = 1.4f * (float)(1 << o);
    int t = threadIdx.x;   // 512
    int n = 2*r + 1;
    float wv = 0.f;
    if (t < n) { float ft = (float)(t - r) / sigma; wv = expf(-0.5f * ft * ft); }
    __shared__ float red[512];
    red[t] = wv; __syncthreads();
    for (int s = 256; s > 0; s >>= 1) { if (t < s) red[t] += red[t + s]; __syncthreads(); }
    float sum = red[0];
    float* g = gw + o*280;
    for (int i = t; i < 280; i += 512) g[i] = 0.f;
    __syncthreads();
    if (t < n) g[3 + t] = wv / sum;
}

__global__ void minmaxK(const float4* __restrict__ x4, unsigned* minenc, unsigned* maxenc) {
    int ch = blockIdx.y, chunk = blockIdx.x, t = threadIdx.x;
    size_t base = (size_t)ch*(NPX/4) + (size_t)chunk*8192;
    float mn = 3.4e38f, mx = -3.4e38f;
    for (int i = t; i < 8192; i += 256) {
        float4 v = x4[base + i];
        mn = fminf(mn, fminf(fminf(v.x, v.y), fminf(v.z, v.w)));
        mx = fmaxf(mx, fmaxf(fmaxf(v.x, v.y), fmaxf(v.z, v.w)));
    }
    for (int o = 32; o; o >>= 1) { mn = fminf(mn, __shfl_down(mn, o)); mx = fmaxf(mx, __shfl_down(mx, o)); }
    __shared__ float smn[4], smx[4];
    if ((t & 63) == 0) { smn[t >> 6] = mn; smx[t >> 6] = mx; }
    __syncthreads();
    if (t == 0) {
        for (int i = 1; i < 4; i++) { mn = fminf(mn, smn[i]); mx = fmaxf(mx, smx[i]); }
        atomicMin(&minenc[ch], encf(mn));
        atomicMax(&maxenc[ch], encf(mx));
    }
}

__global__ void scaleK(const unsigned* minenc, const unsigned* maxenc, double* gsd) {
    int t = threadIdx.x;
    if (t >= NCH) return;
    double mn = (double)decf(minenc[t]), mx = (double)decf(maxenc[t]);
    gsd[t] = 255.0 / (mx - mn + 1e-12);
}

// Tiled Harris R (fp64) + Laplacian base: 32x32 output tile per block.
// Phase 1: load 36x36 input tile (rows py0-2..py0+33).
// Phase 2: Sobel product maps Pxx/Pyy/Pxy at 33x33 positions (py0-1..py0+31) -- computed ONCE per position.
// Phase 3: 2x2 box sum (reflect of ARRAY positions at the border), R formula, lap, rmax reduce.
__global__ __launch_bounds__(256) void lapRK(const float* __restrict__ x, const double* __restrict__ gsd,
                      float* __restrict__ lap, double* __restrict__ Rb,
                      unsigned long long* __restrict__ rmaxenc) {
    __shared__ float in[36*36];
    __shared__ double Pxx[33*34], Pyy[33*34], Pxy[33*34];
    int ch = blockIdx.z;
    int px0 = blockIdx.x * 32, py0 = blockIdx.y * 32;
    const float* s = x + (size_t)ch*NPX;
    int t = threadIdx.x;
    for (int i = t; i < 36*36; i += 256) {
        int yy = i / 36, xx = i - yy*36;
        in[i] = s[(size_t)refl(py0 - 2 + yy)*W + refl(px0 - 2 + xx)];
    }
    __syncthreads();
    for (int i = t; i < 33*33; i += 256) {
        int ly = i / 33, lx = i - ly*33;
        const float* c = &in[(ly+1)*36 + (lx+1)];  // position (py0-1+ly, px0-1+lx) centered
        double v00 = c[-37], v01 = c[-36], v02 = c[-35];
        double v10 = c[-1],                v12 = c[1];
        double v20 = c[35],  v21 = c[36],  v22 = c[37];
        double ix = (v02 - v00) + 2.0*(v12 - v10) + (v22 - v20);
        double iy = (v20 - v00) + 2.0*(v21 - v01) + (v22 - v02);
        Pxx[ly*34+lx] = ix*ix; Pyy[ly*34+lx] = iy*iy; Pxy[ly*34+lx] = ix*iy;
    }
    __syncthreads();
    double sd = gsd[ch], s2 = sd*sd;
    int tx = t & 31, ty0 = (t >> 5) * 4;
    double m = -1e308;
    #pragma unroll
    for (int q = 0; q < 4; q++) {
        int ly = ty0 + q;
        int gy = py0 + ly, gx = px0 + tx;
        // box source rows (array-position reflect): global {gy?gy-1:1, gy} -> local = g - (py0-1)
        int ya = (gy ? gy-1 : 1) - py0 + 1;
        int yb = ly + 1;
        int xa = (gx ? gx-1 : 1) - px0 + 1;
        int xb = tx + 1;
        double Sxx = (Pxx[ya*34+xa] + Pxx[ya*34+xb]) + (Pxx[yb*34+xa] + Pxx[yb*34+xb]);
        double Syy = (Pyy[ya*34+xa] + Pyy[ya*34+xb]) + (Pyy[yb*34+xa] + Pyy[yb*34+xb]);
        double Sxy = (Pxy[ya*34+xa] + Pxy[ya*34+xb]) + (Pxy[yb*34+xa] + Pxy[yb*34+xb]);
        Sxx *= s2; Syy *= s2; Sxy *= s2;
        double tr = Sxx + Syy;
        double R = Sxx*Syy - Sxy*Sxy - 0.04*tr*tr;
        Rb[(size_t)ch*NPX + (size_t)gy*W + gx] = R;
        const float* c = &in[(ly+2)*36 + (tx+2)];
        double l = 2.0*((double)c[-37] + (double)c[-35] + (double)c[35] + (double)c[37]) - 8.0*(double)c[0];
        lap[(size_t)ch*NPX + (size_t)gy*W + gx] = (float)(sd * l);
        m = fmax(m, R);
    }
    for (int o = 32; o; o >>= 1) m = fmax(m, __shfl_down(m, o));
    __shared__ double sred[4];
    if ((t & 63) == 0) sred[t >> 6] = m;
    __syncthreads();
    if (t == 0) {
        for (int i = 1; i < 4; i++) m = fmax(m, sred[i]);
        atomicMax(&rmaxenc[ch], enc64(m));
    }
}

// fused threshold + 3x3 dilate:  dilate(R) > thr  ==  OR of (R > thr) over the 3x3 window
__global__ __launch_bounds__(256) void maskTK(const double* __restrict__ Rb,
                                              const unsigned long long* __restrict__ rmaxenc,
                                              unsigned char* __restrict__ maskb) {
    __shared__ int bt[34*34];
    int ch = blockIdx.z;
    int px0 = blockIdx.x*32, py0 = blockIdx.y*32;
    double thr = 0.01 * dec64(rmaxenc[ch]);
    const double* R = Rb + (size_t)ch*NPX;
    int t = threadIdx.x;
    for (int i = t; i < 34*34; i += 256) {
        int yy = i / 34, xx = i - yy*34;
        int gy = py0 - 1 + yy, gx = px0 - 1 + xx;
        int v = 0;
        if ((unsigned)gy < 512u && (unsigned)gx < 512u) v = (R[(size_t)gy*W + gx] > thr) ? 1 : 0;
        bt[i] = v;
    }
    __syncthreads();
    int tx = t & 31, ty0 = (t >> 5) * 4;
    #pragma unroll
    for (int q = 0; q < 4; q++) {
        int ly = ty0 + q;
        int c = (ly+1)*34 + tx + 1;
        int v = bt[c-35] | bt[c-34] | bt[c-33] | bt[c-1] | bt[c] | bt[c+1] | bt[c+33] | bt[c+34] | bt[c+35];
        maskb[(size_t)ch*NPX + (size_t)(py0+ly)*W + px0 + tx] = (unsigned char)v;
    }
}

// horizontal blur: 4 rows/block, 4 px/thread sliding window.
// LDS is 4-way SoA (ES[j%4][j/4]) so the four per-iteration reads are stride-4B
// across lanes (conflict-free), replacing the old 16B-stride float4 read (8-way conflict).
__global__ __launch_bounds__(512) void rowblurK(const float* __restrict__ src, float* __restrict__ dst,
                                                const float* __restrict__ gw, int r) {
    int ch = blockIdx.y;
    int row0 = blockIdx.x * 4;
    int t = threadIdx.x;
    int lr = t >> 7, xi = t & 127;
    __shared__ float ES[4][4][200];
    const float* s = src + (size_t)ch*NPX + (size_t)(row0 + lr)*W;
    int n = W + 2*r;
    for (int i = xi; i < 788; i += 128) {
        float v = 0.f;
        if (i < n) v = s[refl(i - r)];
        ES[lr][i & 3][i >> 2] = v;
    }
    __syncthreads();
    float a0 = 0, a1 = 0, a2 = 0, a3 = 0;
    int nb = (2*r + 7) >> 2;
    for (int c2 = 0; c2 < nb; ++c2) {
        float fx = ES[lr][0][xi + c2];
        float fy = ES[lr][1][xi + c2];
        float fz = ES[lr][2][xi + c2];
        float fw = ES[lr][3][xi + c2];
        const float* g0 = gw + 4*c2;   // weights pre-padded with zeros
        a0 = fmaf(g0[3], fx, a0); a1 = fmaf(g0[2], fx, a1); a2 = fmaf(g0[1], fx, a2); a3 = fmaf(g0[0], fx, a3);
        a0 = fmaf(g0[4], fy, a0); a1 = fmaf(g0[3], fy, a1); a2 = fmaf(g0[2], fy, a2); a3 = fmaf(g0[1], fy, a3);
        a0 = fmaf(g0[5], fz, a0); a1 = fmaf(g0[4], fz, a1); a2 = fmaf(g0[3], fz, a2); a3 = fmaf(g0[2], fz, a3);
        a0 = fmaf(g0[6], fw, a0); a1 = fmaf(g0[5], fw, a1); a2 = fmaf(g0[4], fw, a2); a3 = fmaf(g0[3], fw, a3);
    }
    *(float4*)&dst[(size_t)ch*NPX + (size_t)(row0 + lr)*W + xi*4] = make_float4(a0, a1, a2, a3);
}

// vertical blur + mask + sigma*|.| + channel-max + octave-max into out
__global__ __launch_bounds__(256) void colblurK(const float* __restrict__ T, const unsigned char* __restrict__ maskb,
                                                float* __restrict__ out, const float* __restrict__ gw,
                                                int r, float sigma, int write0) {
    extern __shared__ float tile[];   // [rowsA][32]
    int x0 = blockIdx.x * 32;
    int band0 = blockIdx.y * 128;
    int b = blockIdx.z;
    int t = threadIdx.x;
    int tx = t & 31, ys = t >> 5;
    int rowsData = 128 + 2*r;
    int rowsA = rowsData + 4;
    float vm[4][4];
    #pragma unroll
    for (int q = 0; q < 4; q++) { vm[q][0] = 0; vm[q][1] = 0; vm[q][2] = 0; vm[q][3] = 0; }
    for (int c = 0; c < 3; ++c) {
        int ch = b*3 + c;
        __syncthreads();
        const float* src = T + (size_t)ch*NPX;
        for (int i = t; i < rowsA*32; i += 256) {
            int ly = i >> 5, x = i & 31;
            float v = 0.f;
            if (ly < rowsData) v = src[(size_t)refl(band0 - r + ly)*W + x0 + x];
            tile[i] = v;
        }
        __syncthreads();
        const unsigned char* mrow = maskb + (size_t)ch*NPX;
        #pragma unroll
        for (int q = 0; q < 4; ++q) {
            int j0 = ys*16 + q*4;
            int gy0 = band0 + j0;
            unsigned m0 = mrow[(size_t)(gy0+0)*W + x0 + tx];
            unsigned m1 = mrow[(size_t)(gy0+1)*W + x0 + tx];
            unsigned m2 = mrow[(size_t)(gy0+2)*W + x0 + tx];
            unsigned m3 = mrow[(size_t)(gy0+3)*W + x0 + tx];
            if (__any((int)(m0 | m1 | m2 | m3))) {
                float a0 = 0, a1 = 0, a2 = 0, a3 = 0;
                int nu = 2*r + 4;
                #pragma unroll 4
                for (int u = 0; u < nu; ++u) {
                    float f = tile[(j0 + u)*32 + tx];
                    const float* g0 = gw + u;
                    a0 = fmaf(g0[3], f, a0);
                    a1 = fmaf(g0[2], f, a1);
                    a2 = fmaf(g0[1], f, a2);
                    a3 = fmaf(g0[0], f, a3);
                }
                if (m0) vm[q][0] = fmaxf(vm[q][0], sigma*fabsf(a0));
                if (m1) vm[q][1] = fmaxf(vm[q][1], sigma*fabsf(a1));
                if (m2) vm[q][2] = fmaxf(vm[q][2], sigma*fabsf(a2));
                if (m3) vm[q][3] = fmaxf(vm[q][3], sigma*fabsf(a3));
            }
        }
    }
    float* ob = out + (size_t)b*NPX;
    #pragma unroll
    for (int q = 0; q < 4; q++) {
        int j0 = ys*16 + q*4;
        #pragma unroll
        for (int m = 0; m < 4; m++) {
            size_t idx = (size_t)(band0 + j0 + m)*W + x0 + tx;
            float v = vm[q][m];
            if (!write0) v = fmaxf(v, ob[idx]);
            ob[idx] = v;
        }
    }
}

extern "C" void kernel_launch(void* const* d_in, const int* in_sizes, int n_in,
                              void* d_out, int out_size, void* d_ws, size_t ws_size,
                              hipStream_t stream) {
    const float* x = (const float*)d_in[0];
    float* out = (float*)d_out;
    char* w = (char*)d_ws;
    unsigned* minenc           = (unsigned*)(w + 1024);
    unsigned* maxenc           = (unsigned*)(w + 1280);
    unsigned long long* rmaxenc= (unsigned long long*)(w + 1536);
    double*  gsd               = (double*)(w + 256);
    float*   gw                = (float*)(w + 2048);                 // 6*280 floats
    float*   lap               = (float*)(w + 16384);                // 50331648 B
    double*  Rb                = (double*)(w + 16384 + 50331648);    // 100663296 B
    float*   T                 = (float*)Rb;                         // reused after maskTK
    unsigned char* maskb       = (unsigned char*)(w + 16384 + 50331648 + 100663296); // 12582912 B

    initK<<<1, 64, 0, stream>>>(minenc, maxenc, rmaxenc);
    gaussK<<<6, 512, 0, stream>>>(gw);
    minmaxK<<<dim3(8, 48), 256, 0, stream>>>((const float4*)x, minenc, maxenc);
    scaleK<<<1, 64, 0, stream>>>(minenc, maxenc, gsd);
    lapRK<<<dim3(16, 16, 48), 256, 0, stream>>>(x, gsd, lap, Rb, rmaxenc);
    maskTK<<<dim3(16, 16, 48), 256, 0, stream>>>(Rb, rmaxenc, maskb);

    const int rr[6] = {4, 8, 17, 34, 67, 134};
    for (int o = 0; o < 6; ++o) {
        int r = rr[o];
        float sigma = 1.4f * (float)(1 << o);
        rowblurK<<<dim3(128, 48), 512, 0, stream>>>(lap, T, gw + o*280, r);
        int rowsA = 128 + 2*r + 4;
        size_t lds = (size_t)rowsA * 32 * 4;
        colblurK<<<dim3(16, 4, 16), 256, lds, stream>>>(T, maskb, out, gw + o*280, r, sigma, o == 0 ? 1 : 0);
    }
}

// Round 3
// 831.633 us; speedup vs baseline: 1.5232x; 1.1943x over previous
//
#include <hip/hip_runtime.h>

#define W 512
#define NPX (512*512)
#define NCH 48
#define NBATCH 16

// reflect-101 index mapping into [0,511]; valid for i in [-511, 1022]
__device__ __forceinline__ int refl(int i) {
    int a = i < 0 ? -i : i;
    int b = 1022 - a;
    return a < b ? a : b;
}
__device__ __forceinline__ unsigned encf(float f) {
    unsigned u = __float_as_uint(f);
    return (u & 0x80000000u) ? ~u : (u | 0x80000000u);
}
__device__ __forceinline__ float decf(unsigned e) {
    unsigned u = (e & 0x80000000u) ? (e & 0x7FFFFFFFu) : ~e;
    return __uint_as_float(u);
}
__device__ __forceinline__ unsigned long long enc64(double d) {
    unsigned long long u = (unsigned long long)__double_as_longlong(d);
    return (u & 0x8000000000000000ULL) ? ~u : (u | 0x8000000000000000ULL);
}
__device__ __forceinline__ double dec64(unsigned long long e) {
    unsigned long long u = (e & 0x8000000000000000ULL) ? (e & 0x7FFFFFFFFFFFFFFFULL) : ~e;
    return __longlong_as_double((long long)u);
}

__global__ void initK(unsigned* minenc, unsigned* maxenc, unsigned long long* rmaxenc) {
    int t = threadIdx.x;
    if (t < NCH) { minenc[t] = 0xFFFFFFFFu; maxenc[t] = 0u; rmaxenc[t] = 0ULL; }
}

// weights: gw[o*288 + k] = g[k] for k in [0, 2r], zero elsewhere (k < 288)
__global__ void gaussK(float* gw) {
    int o = blockIdx.x;
    const int rr[6] = {4, 8, 17, 34, 67, 134};
    int r = rr[o];
    float sigma = 1.4f * (float)(1 << o);
    int t = threadIdx.x;   // 512
    int n = 2*r + 1;
    float wv = 0.f;
    if (t < n) { float ft = (float)(t - r) / sigma; wv = expf(-0.5f * ft * ft); }
    __shared__ float red[512];
    red[t] = wv; __syncthreads();
    for (int s = 256; s > 0; s >>= 1) { if (t < s) red[t] += red[t + s]; __syncthreads(); }
    float sum = red[0];
    float* g = gw + o*288;
    if (t < 288) g[t] = (t < n) ? wv / sum : 0.f;
}

__global__ void minmaxK(const float4* __restrict__ x4, unsigned* minenc, unsigned* maxenc) {
    int ch = blockIdx.y, chunk = blockIdx.x, t = threadIdx.x;
    size_t base = (size_t)ch*(NPX/4) + (size_t)chunk*8192;
    float mn = 3.4e38f, mx = -3.4e38f;
    for (int i = t; i < 8192; i += 256) {
        float4 v = x4[base + i];
        mn = fminf(mn, fminf(fminf(v.x, v.y), fminf(v.z, v.w)));
        mx = fmaxf(mx, fmaxf(fmaxf(v.x, v.y), fmaxf(v.z, v.w)));
    }
    for (int o = 32; o; o >>= 1) { mn = fminf(mn, __shfl_down(mn, o)); mx = fmaxf(mx, __shfl_down(mx, o)); }
    __shared__ float smn[4], smx[4];
    if ((t & 63) == 0) { smn[t >> 6] = mn; smx[t >> 6] = mx; }
    __syncthreads();
    if (t == 0) {
        for (int i = 1; i < 4; i++) { mn = fminf(mn, smn[i]); mx = fmaxf(mx, smx[i]); }
        atomicMin(&minenc[ch], encf(mn));
        atomicMax(&maxenc[ch], encf(mx));
    }
}

__global__ void scaleK(const unsigned* minenc, const unsigned* maxenc, double* gsd) {
    int t = threadIdx.x;
    if (t >= NCH) return;
    double mn = (double)decf(minenc[t]), mx = (double)decf(maxenc[t]);
    gsd[t] = 255.0 / (mx - mn + 1e-12);
}

// Tiled Harris R (fp64) + Laplacian base: 32x32 output tile per block.
__global__ __launch_bounds__(256) void lapRK(const float* __restrict__ x, const double* __restrict__ gsd,
                      float* __restrict__ lap, double* __restrict__ Rb,
                      unsigned long long* __restrict__ rmaxenc) {
    __shared__ float in[36*36];
    __shared__ double Pxx[33*34], Pyy[33*34], Pxy[33*34];
    int ch = blockIdx.z;
    int px0 = blockIdx.x * 32, py0 = blockIdx.y * 32;
    const float* s = x + (size_t)ch*NPX;
    int t = threadIdx.x;
    for (int i = t; i < 36*36; i += 256) {
        int yy = i / 36, xx = i - yy*36;
        in[i] = s[(size_t)refl(py0 - 2 + yy)*W + refl(px0 - 2 + xx)];
    }
    __syncthreads();
    for (int i = t; i < 33*33; i += 256) {
        int ly = i / 33, lx = i - ly*33;
        const float* c = &in[(ly+1)*36 + (lx+1)];
        double v00 = c[-37], v01 = c[-36], v02 = c[-35];
        double v10 = c[-1],                v12 = c[1];
        double v20 = c[35],  v21 = c[36],  v22 = c[37];
        double ix = (v02 - v00) + 2.0*(v12 - v10) + (v22 - v20);
        double iy = (v20 - v00) + 2.0*(v21 - v01) + (v22 - v02);
        Pxx[ly*34+lx] = ix*ix; Pyy[ly*34+lx] = iy*iy; Pxy[ly*34+lx] = ix*iy;
    }
    __syncthreads();
    double sd = gsd[ch], s2 = sd*sd;
    int tx = t & 31, ty0 = (t >> 5) * 4;
    double m = -1e308;
    #pragma unroll
    for (int q = 0; q < 4; q++) {
        int ly = ty0 + q;
        int gy = py0 + ly, gx = px0 + tx;
        int ya = (gy ? gy-1 : 1) - py0 + 1;
        int yb = ly + 1;
        int xa = (gx ? gx-1 : 1) - px0 + 1;
        int xb = tx + 1;
        double Sxx = (Pxx[ya*34+xa] + Pxx[ya*34+xb]) + (Pxx[yb*34+xa] + Pxx[yb*34+xb]);
        double Syy = (Pyy[ya*34+xa] + Pyy[ya*34+xb]) + (Pyy[yb*34+xa] + Pyy[yb*34+xb]);
        double Sxy = (Pxy[ya*34+xa] + Pxy[ya*34+xb]) + (Pxy[yb*34+xa] + Pxy[yb*34+xb]);
        Sxx *= s2; Syy *= s2; Sxy *= s2;
        double tr = Sxx + Syy;
        double R = Sxx*Syy - Sxy*Sxy - 0.04*tr*tr;
        Rb[(size_t)ch*NPX + (size_t)gy*W + gx] = R;
        const float* c = &in[(ly+2)*36 + (tx+2)];
        double l = 2.0*((double)c[-37] + (double)c[-35] + (double)c[35] + (double)c[37]) - 8.0*(double)c[0];
        lap[(size_t)ch*NPX + (size_t)gy*W + gx] = (float)(sd * l);
        m = fmax(m, R);
    }
    for (int o = 32; o; o >>= 1) m = fmax(m, __shfl_down(m, o));
    __shared__ double sred[4];
    if ((t & 63) == 0) sred[t >> 6] = m;
    __syncthreads();
    if (t == 0) {
        for (int i = 1; i < 4; i++) m = fmax(m, sred[i]);
        atomicMax(&rmaxenc[ch], enc64(m));
    }
}

// fused threshold + 3x3 dilate
__global__ __launch_bounds__(256) void maskTK(const double* __restrict__ Rb,
                                              const unsigned long long* __restrict__ rmaxenc,
                                              unsigned char* __restrict__ maskb) {
    __shared__ int bt[34*34];
    int ch = blockIdx.z;
    int px0 = blockIdx.x*32, py0 = blockIdx.y*32;
    double thr = 0.01 * dec64(rmaxenc[ch]);
    const double* R = Rb + (size_t)ch*NPX;
    int t = threadIdx.x;
    for (int i = t; i < 34*34; i += 256) {
        int yy = i / 34, xx = i - yy*34;
        int gy = py0 - 1 + yy, gx = px0 - 1 + xx;
        int v = 0;
        if ((unsigned)gy < 512u && (unsigned)gx < 512u) v = (R[(size_t)gy*W + gx] > thr) ? 1 : 0;
        bt[i] = v;
    }
    __syncthreads();
    int tx = t & 31, ty0 = (t >> 5) * 4;
    #pragma unroll
    for (int q = 0; q < 4; q++) {
        int ly = ty0 + q;
        int c = (ly+1)*34 + tx + 1;
        int v = bt[c-35] | bt[c-34] | bt[c-33] | bt[c-1] | bt[c] | bt[c+1] | bt[c+33] | bt[c+34] | bt[c+35];
        maskb[(size_t)ch*NPX + (size_t)(py0+ly)*W + px0 + tx] = (unsigned char)v;
    }
}

// horizontal blur: 8 rows/block, 16 px/thread, 16-tap chunks.
// E stored 16-way SoA: ES[row][j%16][j/16]; stride 50 dwords (50%32==18) makes
// both staging writes and reads bank-conflict-free. Weights staged in LDS,
// read as broadcast with compile-time offsets.
__global__ __launch_bounds__(256) void rowblurK(const float* __restrict__ src, float* __restrict__ dst,
                                                const float* __restrict__ gwo, int r, int nc2) {
    __shared__ float ES[8][16][50];
    __shared__ float wl[288];
    int ch = blockIdx.y;
    int row0 = blockIdx.x * 8;
    int t = threadIdx.x;
    int lr = t >> 5, xi = t & 31;
    for (int i = t; i < 288; i += 256) wl[i] = gwo[i];
    const float* s = src + (size_t)ch*NPX + (size_t)(row0 + lr)*W;
    int n = W + 2*r;
    for (int j = xi; j < 800; j += 32) {
        float v = (j < n) ? s[refl(j - r)] : 0.f;
        ES[lr][j & 15][j >> 4] = v;
    }
    __syncthreads();
    float a[16];
    #pragma unroll
    for (int m = 0; m < 16; m++) a[m] = 0.f;
    for (int cc = 0; cc < nc2; ++cc) {
        float wv[16], f[31];
        #pragma unroll
        for (int i = 0; i < 16; i++) wv[i] = wl[16*cc + i];
        #pragma unroll
        for (int j = 0; j < 31; j++) f[j] = ES[lr][j & 15][xi + cc + (j >> 4)];
        #pragma unroll
        for (int m = 0; m < 16; m++) {
            #pragma unroll
            for (int i = 0; i < 16; i++) a[m] = fmaf(wv[i], f[m + i], a[m]);
        }
    }
    float4* d4 = (float4*)(dst + (size_t)ch*NPX + (size_t)(row0 + lr)*W + xi*16);
    d4[0] = make_float4(a[0],  a[1],  a[2],  a[3]);
    d4[1] = make_float4(a[4],  a[5],  a[6],  a[7]);
    d4[2] = make_float4(a[8],  a[9],  a[10], a[11]);
    d4[3] = make_float4(a[12], a[13], a[14], a[15]);
}

// vertical blur + mask + sigma*|.| + channel-max + octave-max.
// 128-row band x 32 cols per block; 16 rows/thread; 16-tap chunks from linear tile.
__global__ __launch_bounds__(256) void colblurK(const float* __restrict__ T, const unsigned char* __restrict__ maskb,
                                                float* __restrict__ out, const float* __restrict__ gwo,
                                                int r, int nc2, int rowsAlloc, float sigma, int write0) {
    extern __shared__ float tile[];   // [rowsAlloc][32]
    __shared__ float wl[288];
    int x0 = blockIdx.x * 32;
    int band0 = blockIdx.y * 128;
    int b = blockIdx.z;
    int t = threadIdx.x;
    int tx = t & 31, ys = t >> 5;
    int j0 = ys * 16;
    int rowsData = 128 + 2*r;
    for (int i = t; i < 288; i += 256) wl[i] = gwo[i];
    float vm[16];
    #pragma unroll
    for (int m = 0; m < 16; m++) vm[m] = 0.f;
    for (int c = 0; c < 3; ++c) {
        int ch = b*3 + c;
        __syncthreads();
        const float* src = T + (size_t)ch*NPX;
        int tot = rowsAlloc * 32;
        for (int i = t; i < tot; i += 256) {
            int ly = i >> 5, x = i & 31;
            tile[i] = (ly < rowsData) ? src[(size_t)refl(band0 - r + ly)*W + x0 + x] : 0.f;
        }
        __syncthreads();
        const unsigned char* mrow = maskb + (size_t)ch*NPX + (size_t)(band0 + j0)*W + x0 + tx;
        unsigned mkbits = 0;
        #pragma unroll
        for (int m = 0; m < 16; m++) mkbits |= (mrow[(size_t)m*W] ? 1u : 0u) << m;
        unsigned long long bal = __ballot(mkbits != 0);
        bool act = ((bal >> (t & 32)) & 0xFFFFFFFFull) != 0;
        if (act) {
            float a[16];
            #pragma unroll
            for (int m = 0; m < 16; m++) a[m] = 0.f;
            const float* tb = tile + j0*32 + tx;
            for (int cc = 0; cc < nc2; ++cc) {
                float wv[16], f[31];
                #pragma unroll
                for (int i = 0; i < 16; i++) wv[i] = wl[16*cc + i];
                const float* tc = tb + 16*cc*32;
                #pragma unroll
                for (int j = 0; j < 31; j++) f[j] = tc[j * 32];
                #pragma unroll
                for (int m = 0; m < 16; m++) {
                    #pragma unroll
                    for (int i = 0; i < 16; i++) a[m] = fmaf(wv[i], f[m + i], a[m]);
                }
            }
            #pragma unroll
            for (int m = 0; m < 16; m++)
                if (mkbits & (1u << m)) vm[m] = fmaxf(vm[m], sigma * fabsf(a[m]));
        }
    }
    float* ob = out + (size_t)b*NPX + (size_t)(band0 + j0)*W + x0 + tx;
    #pragma unroll
    for (int m = 0; m < 16; m++) {
        float v = vm[m];
        if (!write0) v = fmaxf(v, ob[(size_t)m*W]);
        ob[(size_t)m*W] = v;
    }
}

extern "C" void kernel_launch(void* const* d_in, const int* in_sizes, int n_in,
                              void* d_out, int out_size, void* d_ws, size_t ws_size,
                              hipStream_t stream) {
    const float* x = (const float*)d_in[0];
    float* out = (float*)d_out;
    char* w = (char*)d_ws;
    unsigned* minenc           = (unsigned*)(w + 1024);
    unsigned* maxenc           = (unsigned*)(w + 1280);
    unsigned long long* rmaxenc= (unsigned long long*)(w + 1536);
    double*  gsd               = (double*)(w + 256);
    float*   gw                = (float*)(w + 2048);                 // 6*288 floats
    float*   lap               = (float*)(w + 16384);                // 50331648 B
    double*  Rb                = (double*)(w + 16384 + 50331648);    // 100663296 B
    float*   T                 = (float*)Rb;                         // reused after maskTK
    unsigned char* maskb       = (unsigned char*)(w + 16384 + 50331648 + 100663296); // 12582912 B

    initK<<<1, 64, 0, stream>>>(minenc, maxenc, rmaxenc);
    gaussK<<<6, 512, 0, stream>>>(gw);
    minmaxK<<<dim3(8, 48), 256, 0, stream>>>((const float4*)x, minenc, maxenc);
    scaleK<<<1, 64, 0, stream>>>(minenc, maxenc, gsd);
    lapRK<<<dim3(16, 16, 48), 256, 0, stream>>>(x, gsd, lap, Rb, rmaxenc);
    maskTK<<<dim3(16, 16, 48), 256, 0, stream>>>(Rb, rmaxenc, maskb);

    const int rr[6] = {4, 8, 17, 34, 67, 134};
    for (int o = 0; o < 6; ++o) {
        int r = rr[o];
        int nc2 = (2*r + 1 + 15) / 16;
        float sigma = 1.4f * (float)(1 << o);
        rowblurK<<<dim3(64, 48), 256, 0, stream>>>(lap, T, gw + o*288, r, nc2);
        int rowsAlloc = 16*nc2 + 128;
        size_t lds = (size_t)rowsAlloc * 32 * 4;
        colblurK<<<dim3(16, 4, 16), 256, lds, stream>>>(T, maskb, out, gw + o*288, r, nc2, rowsAlloc, sigma, o == 0 ? 1 : 0);
    }
}

// Round 4
// 702.783 us; speedup vs baseline: 1.8024x; 1.1833x over previous
//
#include <hip/hip_runtime.h>

#define W 512
#define NPX (512*512)
#define NCH 48
#define NBATCH 16

// reflect-101 index mapping into [0,511]; valid for i in [-511, 1022]
__device__ __forceinline__ int refl(int i) {
    int a = i < 0 ? -i : i;
    int b = 1022 - a;
    return a < b ? a : b;
}
__device__ __forceinline__ unsigned encf(float f) {
    unsigned u = __float_as_uint(f);
    return (u & 0x80000000u) ? ~u : (u | 0x80000000u);
}
__device__ __forceinline__ float decf(unsigned e) {
    unsigned u = (e & 0x80000000u) ? (e & 0x7FFFFFFFu) : ~e;
    return __uint_as_float(u);
}
__device__ __forceinline__ unsigned long long enc64(double d) {
    unsigned long long u = (unsigned long long)__double_as_longlong(d);
    return (u & 0x8000000000000000ULL) ? ~u : (u | 0x8000000000000000ULL);
}
__device__ __forceinline__ double dec64(unsigned long long e) {
    unsigned long long u = (e & 0x8000000000000000ULL) ? (e & 0x7FFFFFFFFFFFFFFFULL) : ~e;
    return __longlong_as_double((long long)u);
}

__global__ void initK(unsigned* minenc, unsigned* maxenc, unsigned long long* rmaxenc) {
    int t = threadIdx.x;
    if (t < NCH) { minenc[t] = 0xFFFFFFFFu; maxenc[t] = 0u; rmaxenc[t] = 0ULL; }
}

// weights: gw[o*288 + k] = g[k] for k in [0, 2r], zero elsewhere (k < 288)
__global__ void gaussK(float* gw) {
    int o = blockIdx.x;
    const int rr[6] = {4, 8, 17, 34, 67, 134};
    int r = rr[o];
    float sigma = 1.4f * (float)(1 << o);
    int t = threadIdx.x;   // 512
    int n = 2*r + 1;
    float wv = 0.f;
    if (t < n) { float ft = (float)(t - r) / sigma; wv = expf(-0.5f * ft * ft); }
    __shared__ float red[512];
    red[t] = wv; __syncthreads();
    for (int s = 256; s > 0; s >>= 1) { if (t < s) red[t] += red[t + s]; __syncthreads(); }
    float sum = red[0];
    float* g = gw + o*288;
    if (t < 288) g[t] = (t < n) ? wv / sum : 0.f;
}

__global__ void minmaxK(const float4* __restrict__ x4, unsigned* minenc, unsigned* maxenc) {
    int ch = blockIdx.y, chunk = blockIdx.x, t = threadIdx.x;
    size_t base = (size_t)ch*(NPX/4) + (size_t)chunk*8192;
    float mn = 3.4e38f, mx = -3.4e38f;
    for (int i = t; i < 8192; i += 256) {
        float4 v = x4[base + i];
        mn = fminf(mn, fminf(fminf(v.x, v.y), fminf(v.z, v.w)));
        mx = fmaxf(mx, fmaxf(fmaxf(v.x, v.y), fmaxf(v.z, v.w)));
    }
    for (int o = 32; o; o >>= 1) { mn = fminf(mn, __shfl_down(mn, o)); mx = fmaxf(mx, __shfl_down(mx, o)); }
    __shared__ float smn[4], smx[4];
    if ((t & 63) == 0) { smn[t >> 6] = mn; smx[t >> 6] = mx; }
    __syncthreads();
    if (t == 0) {
        for (int i = 1; i < 4; i++) { mn = fminf(mn, smn[i]); mx = fmaxf(mx, smx[i]); }
        atomicMin(&minenc[ch], encf(mn));
        atomicMax(&maxenc[ch], encf(mx));
    }
}

__global__ void scaleK(const unsigned* minenc, const unsigned* maxenc, double* gsd) {
    int t = threadIdx.x;
    if (t >= NCH) return;
    double mn = (double)decf(minenc[t]), mx = (double)decf(maxenc[t]);
    gsd[t] = 255.0 / (mx - mn + 1e-12);
}

// Tiled Harris R (fp64) + Laplacian base: 32x32 output tile per block.
__global__ __launch_bounds__(256) void lapRK(const float* __restrict__ x, const double* __restrict__ gsd,
                      float* __restrict__ lap, double* __restrict__ Rb,
                      unsigned long long* __restrict__ rmaxenc) {
    __shared__ float in[36*36];
    __shared__ double Pxx[33*34], Pyy[33*34], Pxy[33*34];
    int ch = blockIdx.z;
    int px0 = blockIdx.x * 32, py0 = blockIdx.y * 32;
    const float* s = x + (size_t)ch*NPX;
    int t = threadIdx.x;
    for (int i = t; i < 36*36; i += 256) {
        int yy = i / 36, xx = i - yy*36;
        in[i] = s[(size_t)refl(py0 - 2 + yy)*W + refl(px0 - 2 + xx)];
    }
    __syncthreads();
    for (int i = t; i < 33*33; i += 256) {
        int ly = i / 33, lx = i - ly*33;
        const float* c = &in[(ly+1)*36 + (lx+1)];
        double v00 = c[-37], v01 = c[-36], v02 = c[-35];
        double v10 = c[-1],                v12 = c[1];
        double v20 = c[35],  v21 = c[36],  v22 = c[37];
        double ix = (v02 - v00) + 2.0*(v12 - v10) + (v22 - v20);
        double iy = (v20 - v00) + 2.0*(v21 - v01) + (v22 - v02);
        Pxx[ly*34+lx] = ix*ix; Pyy[ly*34+lx] = iy*iy; Pxy[ly*34+lx] = ix*iy;
    }
    __syncthreads();
    double sd = gsd[ch], s2 = sd*sd;
    int tx = t & 31, ty0 = (t >> 5) * 4;
    double m = -1e308;
    #pragma unroll
    for (int q = 0; q < 4; q++) {
        int ly = ty0 + q;
        int gy = py0 + ly, gx = px0 + tx;
        int ya = (gy ? gy-1 : 1) - py0 + 1;
        int yb = ly + 1;
        int xa = (gx ? gx-1 : 1) - px0 + 1;
        int xb = tx + 1;
        double Sxx = (Pxx[ya*34+xa] + Pxx[ya*34+xb]) + (Pxx[yb*34+xa] + Pxx[yb*34+xb]);
        double Syy = (Pyy[ya*34+xa] + Pyy[ya*34+xb]) + (Pyy[yb*34+xa] + Pyy[yb*34+xb]);
        double Sxy = (Pxy[ya*34+xa] + Pxy[ya*34+xb]) + (Pxy[yb*34+xa] + Pxy[yb*34+xb]);
        Sxx *= s2; Syy *= s2; Sxy *= s2;
        double tr = Sxx + Syy;
        double R = Sxx*Syy - Sxy*Sxy - 0.04*tr*tr;
        Rb[(size_t)ch*NPX + (size_t)gy*W + gx] = R;
        const float* c = &in[(ly+2)*36 + (tx+2)];
        double l = 2.0*((double)c[-37] + (double)c[-35] + (double)c[35] + (double)c[37]) - 8.0*(double)c[0];
        lap[(size_t)ch*NPX + (size_t)gy*W + gx] = (float)(sd * l);
        m = fmax(m, R);
    }
    for (int o = 32; o; o >>= 1) m = fmax(m, __shfl_down(m, o));
    __shared__ double sred[4];
    if ((t & 63) == 0) sred[t >> 6] = m;
    __syncthreads();
    if (t == 0) {
        for (int i = 1; i < 4; i++) m = fmax(m, sred[i]);
        atomicMax(&rmaxenc[ch], enc64(m));
    }
}

// fused threshold + 3x3 dilate
__global__ __launch_bounds__(256) void maskTK(const double* __restrict__ Rb,
                                              const unsigned long long* __restrict__ rmaxenc,
                                              unsigned char* __restrict__ maskb) {
    __shared__ int bt[34*34];
    int ch = blockIdx.z;
    int px0 = blockIdx.x*32, py0 = blockIdx.y*32;
    double thr = 0.01 * dec64(rmaxenc[ch]);
    const double* R = Rb + (size_t)ch*NPX;
    int t = threadIdx.x;
    for (int i = t; i < 34*34; i += 256) {
        int yy = i / 34, xx = i - yy*34;
        int gy = py0 - 1 + yy, gx = px0 - 1 + xx;
        int v = 0;
        if ((unsigned)gy < 512u && (unsigned)gx < 512u) v = (R[(size_t)gy*W + gx] > thr) ? 1 : 0;
        bt[i] = v;
    }
    __syncthreads();
    int tx = t & 31, ty0 = (t >> 5) * 4;
    #pragma unroll
    for (int q = 0; q < 4; q++) {
        int ly = ty0 + q;
        int c = (ly+1)*34 + tx + 1;
        int v = bt[c-35] | bt[c-34] | bt[c-33] | bt[c-1] | bt[c] | bt[c+1] | bt[c+33] | bt[c+34] | bt[c+35];
        maskb[(size_t)ch*NPX + (size_t)(py0+ly)*W + px0 + tx] = (unsigned char)v;
    }
}

// horizontal blur: 8 rows/block, 16 px/thread, 16-tap chunks.
// ES SoA [8][16][49] (26.2 KB total w/ wl) -> 6 blocks/CU; grid 12/CU = two exact rounds.
__global__ __launch_bounds__(256) void rowblurK(const float* __restrict__ src, float* __restrict__ dst,
                                                const float* __restrict__ gwo, int r, int nc2) {
    __shared__ float ES[8][16][49];
    __shared__ float wl[272];
    int ch = blockIdx.y;
    int row0 = blockIdx.x * 8;
    int t = threadIdx.x;
    int lr = t >> 5, xi = t & 31;
    for (int i = t; i < 272; i += 256) wl[i] = gwo[i];
    const float* s = src + (size_t)ch*NPX + (size_t)(row0 + lr)*W;
    int n = W + 2*r;
    for (int j = xi; j < 784; j += 32) {
        float v = (j < n) ? s[refl(j - r)] : 0.f;
        ES[lr][j & 15][j >> 4] = v;
    }
    __syncthreads();
    float a[16];
    #pragma unroll
    for (int m = 0; m < 16; m++) a[m] = 0.f;
    for (int cc = 0; cc < nc2; ++cc) {
        float wv[16], f[31];
        #pragma unroll
        for (int i = 0; i < 16; i++) wv[i] = wl[16*cc + i];
        #pragma unroll
        for (int j = 0; j < 31; j++) f[j] = ES[lr][j & 15][xi + cc + (j >> 4)];
        #pragma unroll
        for (int m = 0; m < 16; m++) {
            #pragma unroll
            for (int i = 0; i < 16; i++) a[m] = fmaf(wv[i], f[m + i], a[m]);
        }
    }
    float4* d4 = (float4*)(dst + (size_t)ch*NPX + (size_t)(row0 + lr)*W + xi*16);
    d4[0] = make_float4(a[0],  a[1],  a[2],  a[3]);
    d4[1] = make_float4(a[4],  a[5],  a[6],  a[7]);
    d4[2] = make_float4(a[8],  a[9],  a[10], a[11]);
    d4[3] = make_float4(a[12], a[13], a[14], a[15]);
}

// vertical blur + mask + sigma*|.| + channel-max + octave-max.
// Thread owns 4 cols (float4) x RPT rows; 8 col-groups x 32 row-groups = 256 thr.
// Tile row stride 36 floats: 16B-aligned b128 reads, 2-way bank aliasing (free).
// RPT=4/CHUNK=8: band 128, LDS <=39.2KB -> 4 blocks/CU, grid 4/CU exact.
// RPT=8/CHUNK=16 (o5): band 256, LDS 77KB -> 2 blocks/CU, grid 2/CU exact.
template<int RPT, int CHUNK>
__global__ __launch_bounds__(256, (RPT == 4) ? 4 : 2)
void colblurK(const float* __restrict__ T, const unsigned char* __restrict__ maskb,
              float* __restrict__ out, const float* __restrict__ gwo,
              int r, int nchunk, int rowsAlloc, float sigma, int write0) {
    extern __shared__ __align__(16) float tile[];   // [rowsAlloc][36] + wl[288]
    float* wl = tile + rowsAlloc*36;
    const int BAND = RPT*32;
    int x0 = blockIdx.x * 32;
    int band0 = blockIdx.y * BAND;
    int b = blockIdx.z;
    int t = threadIdx.x;
    int cg = t & 7, rg = t >> 3;
    int j0 = rg * RPT;
    int rowsData = BAND + 2*r;
    for (int i = t; i < 288; i += 256) wl[i] = gwo[i];
    float4 vm[RPT];
    #pragma unroll
    for (int m = 0; m < RPT; m++) vm[m] = make_float4(0.f, 0.f, 0.f, 0.f);
    for (int c = 0; c < 3; ++c) {
        int ch = b*3 + c;
        __syncthreads();
        const float* src = T + (size_t)ch*NPX;
        for (int ly = rg; ly < rowsAlloc; ly += 32) {
            float4 v = make_float4(0.f, 0.f, 0.f, 0.f);
            if (ly < rowsData) v = *(const float4*)(src + (size_t)refl(band0 - r + ly)*W + x0 + 4*cg);
            *(float4*)(tile + ly*36 + 4*cg) = v;
        }
        __syncthreads();
        const unsigned char* mp = maskb + (size_t)ch*NPX + (size_t)(band0 + j0)*W + x0 + 4*cg;
        unsigned mk = 0;
        #pragma unroll
        for (int m = 0; m < RPT; m++) {
            uchar4 u = *(const uchar4*)(mp + (size_t)m*W);
            mk |= ((u.x ? 1u : 0u) | (u.y ? 2u : 0u) | (u.z ? 4u : 0u) | (u.w ? 8u : 0u)) << (4*m);
        }
        if (__any((int)(mk != 0))) {
            float4 a[RPT];
            #pragma unroll
            for (int m = 0; m < RPT; m++) a[m] = make_float4(0.f, 0.f, 0.f, 0.f);
            const float* tb = tile + j0*36 + 4*cg;
            for (int cc = 0; cc < nchunk; ++cc) {
                const float* tc = tb + CHUNK*cc*36;
                float4 f[RPT + CHUNK - 1];
                #pragma unroll
                for (int j = 0; j < RPT + CHUNK - 1; j++) f[j] = *(const float4*)(tc + j*36);
                float wv[CHUNK];
                #pragma unroll
                for (int q = 0; q < CHUNK/4; q++) {
                    float4 w4 = *(const float4*)(wl + CHUNK*cc + 4*q);
                    wv[4*q] = w4.x; wv[4*q+1] = w4.y; wv[4*q+2] = w4.z; wv[4*q+3] = w4.w;
                }
                #pragma unroll
                for (int m = 0; m < RPT; m++) {
                    #pragma unroll
                    for (int i = 0; i < CHUNK; i++) {
                        a[m].x = fmaf(wv[i], f[m+i].x, a[m].x);
                        a[m].y = fmaf(wv[i], f[m+i].y, a[m].y);
                        a[m].z = fmaf(wv[i], f[m+i].z, a[m].z);
                        a[m].w = fmaf(wv[i], f[m+i].w, a[m].w);
                    }
                }
            }
            #pragma unroll
            for (int m = 0; m < RPT; m++) {
                if (mk & (1u << (4*m+0))) vm[m].x = fmaxf(vm[m].x, sigma*fabsf(a[m].x));
                if (mk & (1u << (4*m+1))) vm[m].y = fmaxf(vm[m].y, sigma*fabsf(a[m].y));
                if (mk & (1u << (4*m+2))) vm[m].z = fmaxf(vm[m].z, sigma*fabsf(a[m].z));
                if (mk & (1u << (4*m+3))) vm[m].w = fmaxf(vm[m].w, sigma*fabsf(a[m].w));
            }
        }
    }
    float* ob = out + (size_t)b*NPX + (size_t)(band0 + j0)*W + x0 + 4*cg;
    #pragma unroll
    for (int m = 0; m < RPT; m++) {
        float4 v = vm[m];
        if (!write0) {
            float4 cur = *(const float4*)(ob + (size_t)m*W);
            v.x = fmaxf(v.x, cur.x); v.y = fmaxf(v.y, cur.y);
            v.z = fmaxf(v.z, cur.z); v.w = fmaxf(v.w, cur.w);
        }
        *(float4*)(ob + (size_t)m*W) = v;
    }
}

extern "C" void kernel_launch(void* const* d_in, const int* in_sizes, int n_in,
                              void* d_out, int out_size, void* d_ws, size_t ws_size,
                              hipStream_t stream) {
    const float* x = (const float*)d_in[0];
    float* out = (float*)d_out;
    char* w = (char*)d_ws;
    unsigned* minenc           = (unsigned*)(w + 1024);
    unsigned* maxenc           = (unsigned*)(w + 1280);
    unsigned long long* rmaxenc= (unsigned long long*)(w + 1536);
    double*  gsd               = (double*)(w + 256);
    float*   gw                = (float*)(w + 2048);                 // 6*288 floats
    float*   lap               = (float*)(w + 16384);                // 50331648 B
    double*  Rb                = (double*)(w + 16384 + 50331648);    // 100663296 B
    float*   T                 = (float*)Rb;                         // reused after maskTK
    unsigned char* maskb       = (unsigned char*)(w + 16384 + 50331648 + 100663296); // 12582912 B

    initK<<<1, 64, 0, stream>>>(minenc, maxenc, rmaxenc);
    gaussK<<<6, 512, 0, stream>>>(gw);
    minmaxK<<<dim3(8, 48), 256, 0, stream>>>((const float4*)x, minenc, maxenc);
    scaleK<<<1, 64, 0, stream>>>(minenc, maxenc, gsd);
    lapRK<<<dim3(16, 16, 48), 256, 0, stream>>>(x, gsd, lap, Rb, rmaxenc);
    maskTK<<<dim3(16, 16, 48), 256, 0, stream>>>(Rb, rmaxenc, maskb);

    const int rr[6] = {4, 8, 17, 34, 67, 134};
    for (int o = 0; o < 6; ++o) {
        int r = rr[o];
        int nc16 = (2*r + 1 + 15) / 16;
        float sigma = 1.4f * (float)(1 << o);
        rowblurK<<<dim3(64, 48), 256, 0, stream>>>(lap, T, gw + o*288, r, nc16);
        if (o == 5) {
            int nc = nc16;                       // 17 chunks of 16
            int rowsAlloc = 256 + 16*nc;         // 528
            size_t lds = (size_t)(rowsAlloc*36 + 288) * 4;
            colblurK<8,16><<<dim3(16, 2, 16), 256, lds, stream>>>(T, maskb, out, gw + o*288, r, nc, rowsAlloc, sigma, 0);
        } else {
            int nc = (2*r + 1 + 7) / 8;
            int rowsAlloc = 128 + 8*nc;
            size_t lds = (size_t)(rowsAlloc*36 + 288) * 4;
            colblurK<4,8><<<dim3(16, 4, 16), 256, lds, stream>>>(T, maskb, out, gw + o*288, r, nc, rowsAlloc, sigma, o == 0 ? 1 : 0);
        }
    }
}